// Round 5
// baseline (1116.171 us; speedup 1.0000x reference)
//
#include <hip/hip_runtime.h>
#include <hip/hip_bf16.h>

// Qwen3-Next GatedDeltaNet prefill, B=2, S=2048, HK=16, HV=32, DK=DV=128, K=4.
// Round 9: TLP x2. Round-8 was neutral (650us, VALUBusy 66%): pair-batching
// bought latency overlap but paid equal issue. Remaining 34% stall is filled
// with a second wave per SIMD: 2048 single-wave blocks (was 1024), thread =
// (vcol in 4, kh16 in 16 groups of 8 rows), S[8]/thread, red16 = 4 DPP stages
// (0xB1, 0x4E, row_half_mirror, row_mirror -- valid: lower stages make
// quads/halves uniform). CH_=8 so LDS=17KB -> 8 blocks/CU resident.
// DMA 10 instr/chunk (4K+4Q+1V+1G), 8 stores/chunk -> counted vmcnt(18).
// ds_read granule order r^((kh16>>2)&1): 16 uniq addrs x 4-lane bcast,
// 2-way bank alias = free. Pair math (mini-WY) unchanged.

#define B_    2
#define S_    2048
#define HK_   16
#define HV_   32
#define DK_   128
#define QKV_  8192
#define EPS_  1e-6f
#define SCALE_ 0.08838834764831845f   // 128^-0.5
#define CH_   8
#define NCH_  (S_ / CH_)

#define AS_GLOBAL __attribute__((address_space(1)))
#define AS_LDS    __attribute__((address_space(3)))

__device__ __forceinline__ void gload16(const float* src, float* dst) {
    __builtin_amdgcn_global_load_lds((const AS_GLOBAL void*)src,
                                     (AS_LDS void*)dst, 16, 0, 0);
}
__device__ __forceinline__ void gload4(const float* src, float* dst) {
    __builtin_amdgcn_global_load_lds((const AS_GLOBAL void*)src,
                                     (AS_LDS void*)dst, 4, 0, 0);
}

// 16-lane sum over lanes sharing (lane>>4): all stages VALU-latency DPP.
// Stage 3 (xor4) via row_half_mirror (i^7): valid since quads uniform after
// stages 1-2. Stage 4 (xor8) via row_mirror (i^15): valid since 8-lane
// halves uniform after stages 1-3.
__device__ __forceinline__ float red16(float x) {
    int t;
    t = __builtin_amdgcn_update_dpp(0, __float_as_int(x), 0xB1, 0xF, 0xF, true);
    x += __int_as_float(t);                               // + lane^1
    t = __builtin_amdgcn_update_dpp(0, __float_as_int(x), 0x4E, 0xF, 0xF, true);
    x += __int_as_float(t);                               // + lane^2
    t = __builtin_amdgcn_update_dpp(0, __float_as_int(x), 0x141, 0xF, 0xF, true);
    x += __int_as_float(t);                               // + lane^4 (via ^7)
    t = __builtin_amdgcn_update_dpp(0, __float_as_int(x), 0x140, 0xF, 0xF, true);
    x += __int_as_float(t);                               // + lane^8 (via ^15)
    return x;
}

// ---------------------------------------------------------------------------
// Preprocess: y = silu(causal_conv(x)); q/k l2-normalized per 128-ch head,
// q pre-scaled by DK^-0.5. Y layout = x layout: [B*S, 8192].
// grid (4 segs, B*S/4), block 256, 8 ch/thread, 4 tokens/block (rolling hist).
// ---------------------------------------------------------------------------
__global__ __launch_bounds__(256)
void preproc_kernel(const float* __restrict__ x, const float* __restrict__ w,
                    float* __restrict__ Y)
{
    const int seg = blockIdx.x;            // 0:q 1:k 2,3:v
    const int bt0 = blockIdx.y * 4;        // first global row of this block
    const int t0  = bt0 & (S_ - 1);        // token within sequence
    const int tid = threadIdx.x;
    const int c0  = seg * 2048 + tid * 8;

    float4 w4[8];
#pragma unroll
    for (int i = 0; i < 8; ++i)
        w4[i] = *reinterpret_cast<const float4*>(&w[(c0 + i) * 4]);

    float h0[8], h1[8], h2[8], cur[8], y[8];

#pragma unroll
    for (int i = 0; i < 8; ++i) { h0[i] = 0.f; h1[i] = 0.f; h2[i] = 0.f; }
    if (t0 >= 3) {   // t0 is a multiple of 4, so either 0 (all zero) or >=4
        const float* r0 = &x[(size_t)(bt0 - 3) * QKV_ + c0];
        const float* r1 = &x[(size_t)(bt0 - 2) * QKV_ + c0];
        const float* r2 = &x[(size_t)(bt0 - 1) * QKV_ + c0];
#pragma unroll
        for (int i4 = 0; i4 < 2; ++i4) {
            const float4 a = *reinterpret_cast<const float4*>(r0 + i4 * 4);
            const float4 b = *reinterpret_cast<const float4*>(r1 + i4 * 4);
            const float4 c = *reinterpret_cast<const float4*>(r2 + i4 * 4);
            h0[4*i4+0]=a.x; h0[4*i4+1]=a.y; h0[4*i4+2]=a.z; h0[4*i4+3]=a.w;
            h1[4*i4+0]=b.x; h1[4*i4+1]=b.y; h1[4*i4+2]=b.z; h1[4*i4+3]=b.w;
            h2[4*i4+0]=c.x; h2[4*i4+1]=c.y; h2[4*i4+2]=c.z; h2[4*i4+3]=c.w;
        }
    }

#pragma unroll
    for (int tt = 0; tt < 4; ++tt) {
        const float* rc = &x[(size_t)(bt0 + tt) * QKV_ + c0];
#pragma unroll
        for (int i4 = 0; i4 < 2; ++i4) {
            const float4 a = *reinterpret_cast<const float4*>(rc + i4 * 4);
            cur[4*i4+0]=a.x; cur[4*i4+1]=a.y; cur[4*i4+2]=a.z; cur[4*i4+3]=a.w;
        }
#pragma unroll
        for (int i = 0; i < 8; ++i) {
            float v = h0[i]*w4[i].x + h1[i]*w4[i].y + h2[i]*w4[i].z + cur[i]*w4[i].w;
            y[i] = v / (1.f + expf(-v));                 // silu
        }
        if (seg < 2) {                                    // l2norm over 128 ch = 16 lanes
            float s = 0.f;
#pragma unroll
            for (int i = 0; i < 8; ++i) s += y[i] * y[i];
#pragma unroll
            for (int off = 8; off >= 1; off >>= 1)
                s += __shfl_xor(s, off, 64);
            float rn = rsqrtf(s + EPS_);
            if (seg == 0) rn *= SCALE_;
#pragma unroll
            for (int i = 0; i < 8; ++i) y[i] *= rn;
        }
        float4* dst = reinterpret_cast<float4*>(&Y[(size_t)(bt0 + tt) * QKV_ + c0]);
        dst[0] = make_float4(y[0], y[1], y[2], y[3]);
        dst[1] = make_float4(y[4], y[5], y[6], y[7]);
#pragma unroll
        for (int i = 0; i < 8; ++i) { h0[i] = h1[i]; h1[i] = h2[i]; h2[i] = cur[i]; }
    }
}

// ---------------------------------------------------------------------------
// Gating: GB[i] = (exp(-exp(alog)*softplus(a+dt_bias)), sigmoid(b)). [B*S,HV]
// ---------------------------------------------------------------------------
__global__ __launch_bounds__(256)
void gating_kernel(const float* __restrict__ bin, const float* __restrict__ ain,
                   const float* __restrict__ dtb, const float* __restrict__ alg,
                   float2* __restrict__ GB)
{
    const int i = blockIdx.x * 256 + threadIdx.x;
    if (i >= B_ * S_ * HV_) return;
    const int h = i & (HV_ - 1);
    const float av = ain[i] + dtb[h];
    const float sp = (av > 20.f) ? av : log1pf(expf(av));
    GB[i] = make_float2(expf(-expf(alg[h]) * sp), 1.f / (1.f + expf(-bin[i])));
}

// ---------------------------------------------------------------------------
// Recurrence helpers
// ---------------------------------------------------------------------------
__device__ __forceinline__ void lds_load_kqv8(const float* __restrict__ Kt,
                                              const float* __restrict__ Qt,
                                              const float* __restrict__ Vt,
                                              int kh16, int vloc, int sw,
                                              float (&kf)[8], float (&qf)[8],
                                              float& vv)
{
    // granule order (r ^ sw): per-instruction 16 unique addresses (x4 bcast)
    // at 2-way bank aliasing = conflict-free. Register indices STATIC; the
    // per-thread granule permutation is shared by kf/qf/S -> math consistent.
#pragma unroll
    for (int r = 0; r < 2; ++r) {
        const int idx = r ^ sw;                           // LDS address only
        const float4 kq = *reinterpret_cast<const float4*>(Kt + kh16 * 8 + idx * 4);
        const float4 qq = *reinterpret_cast<const float4*>(Qt + kh16 * 8 + idx * 4);
        kf[4*r+0]=kq.x; kf[4*r+1]=kq.y; kf[4*r+2]=kq.z; kf[4*r+3]=kq.w;
        qf[4*r+0]=qq.x; qf[4*r+1]=qq.y; qf[4*r+2]=qq.z; qf[4*r+3]=qq.w;
    }
    vv = Vt[vloc];
}

// One 2-token step (mini-WY). All 8 dots vs S_prev (parallel, one reduction
// latency per pair); scalar resolve; fused 3-FMA S update.
__device__ __forceinline__ void step_pair(float (&S)[8],
    const float (&k0)[8], const float (&q0)[8], float v0,
    const float (&k1)[8], const float (&q1)[8], float v1,
    float4 g,                       // (eg0, b0, eg1, b1)
    int kh16, float* __restrict__ o0p, float* __restrict__ o1p)
{
    float a0 = 0.f, a1 = 0.f, cc = 0.f, u0 = 0.f,
          u1 = 0.f, w00 = 0.f, w10 = 0.f, w11 = 0.f;
#pragma unroll
    for (int j = 0; j < 8; ++j) {
        a0  += k0[j] * S[j];
        a1  += k1[j] * S[j];
        cc  += k1[j] * k0[j];
        u0  += q0[j] * S[j];
        u1  += q1[j] * S[j];
        w00 += q0[j] * k0[j];
        w10 += q1[j] * k0[j];
        w11 += q1[j] * k1[j];
    }
    a0 = red16(a0);  a1 = red16(a1);  cc = red16(cc);  u0 = red16(u0);
    u1 = red16(u1);  w00 = red16(w00); w10 = red16(w10); w11 = red16(w11);

    const float eg0 = g.x, b0 = g.y, eg1 = g.z, b1 = g.w;
    const float d0   = b0 * (v0 - eg0 * a0);
    const float eg01 = eg0 * eg1;
    const float p1   = fmaf(eg1 * cc, d0, eg01 * a1);
    const float d1   = b1 * (v1 - p1);
    const float o0   = fmaf(w00, d0, eg0 * u0);
    const float o1   = fmaf(w11, d1, fmaf(eg1 * w10, d0, eg01 * u1));
    const float bb   = eg1 * d0;
#pragma unroll
    for (int j = 0; j < 8; ++j)
        S[j] = fmaf(eg01, S[j], fmaf(bb, k0[j], d1 * k1[j]));

    if (kh16 == 0) { *o0p = o0; *o1p = o1; }
}

// ---------------------------------------------------------------------------
// Recurrence: grid (HV, B, 32 v-slices) = 2048 single-wave blocks, 64 thr.
// thread = (vcol = vs*4 + lane>>4, kh16 = lane&15); owns S[kh16*8 .. +7][vcol].
// 2 waves/SIMD resident (LDS 17 KB -> 8 blocks/CU): second wave's issue
// fills the first's dependency stalls. 8-token chunks staged to LDS
// (double-buffered) via global_load_lds; chunk c+2 DMA issued after chunk c,
// kept in flight with s_waitcnt vmcnt(18) = 10 loads + 8 o-stores.
// ---------------------------------------------------------------------------
__global__ __launch_bounds__(64, 2)
void recur_kernel(const float* __restrict__ Y, const float2* __restrict__ GB,
                  float* __restrict__ out)
{
    const int h    = blockIdx.x;
    const int b    = blockIdx.y;
    const int vs   = blockIdx.z;           // 0..31, 4 vcols each
    const int hk   = h >> 1;
    const int lane = threadIdx.x;
    const int kh16 = lane & 15;
    const int vloc = lane >> 4;
    const int sw   = (kh16 >> 2) & 1;

    const int qoff0 = hk * DK_;
    const int koff0 = 2048 + hk * DK_;
    const int voff0 = 4096 + h * DK_ + vs * 4;

    // 17408 B static LDS -> 8 blocks/CU co-resident (8*17408 <= 160 KiB)
    __shared__ __align__(16) float Ksm[2][CH_][128];
    __shared__ __align__(16) float Qsm[2][CH_][128];
    __shared__ __align__(16) float Vsm[2][64];    // [tok*4+col], 32 used + dup pad
    __shared__ __align__(16) float Gsm[2][64];    // [tok*2+fld], 16 used + dup pad

    const float* rowBase = Y + (size_t)(b * S_) * QKV_;
    const float* gflat   = (const float*)(GB + (size_t)(b * S_) * HV_ + h);
    float* obase = out + ((size_t)(b * S_) * HV_ + h) * (size_t)DK_ + vs * 4 + vloc;

    auto issue_chunk = [&](int t0, int bsel) {
#pragma unroll
        for (int i = 0; i < 4; ++i)     // K: 4 x 16B-per-lane, 2 tokens each
            gload16(rowBase + (size_t)(t0 + 2 * i + (lane >> 5)) * QKV_
                            + koff0 + (lane & 31) * 4,
                    &Ksm[bsel][2 * i][0]);
#pragma unroll
        for (int i = 0; i < 4; ++i)     // Q: 4 x 16B-per-lane
            gload16(rowBase + (size_t)(t0 + 2 * i + (lane >> 5)) * QKV_
                            + qoff0 + (lane & 31) * 4,
                    &Qsm[bsel][2 * i][0]);
        // V: 8 tok x 4 cols; lanes 0-31 cover it, 32-63 duplicate into pad
        gload4(rowBase + (size_t)(t0 + ((lane >> 2) & 7)) * QKV_
                       + voff0 + (lane & 3),
               &Vsm[bsel][0]);
        // G: 8 tok x (eg,beta); lanes 0-15 cover it, rest duplicate into pad
        gload4(gflat + (size_t)(t0 + ((lane >> 1) & 7)) * (HV_ * 2) + (lane & 1),
               &Gsm[bsel][0]);
    };

    float S[8];
#pragma unroll
    for (int j = 0; j < 8; ++j) S[j] = 0.f;

    issue_chunk(0, 0);
    issue_chunk(CH_, 1);
    asm volatile("s_waitcnt vmcnt(10)" ::: "memory");   // chunk 0 landed

    // pair-level A/B register double buffer
    float k0A[8], q0A[8], k1A[8], q1A[8], v0A, v1A;
    float k0B[8], q0B[8], k1B[8], q1B[8], v0B, v1B;
    float4 gA, gB4;

    for (int c = 0; c < NCH_; ++c) {
        const int bsel = c & 1;
        const int t0   = c * CH_;
        const float (*Kc)[128] = Ksm[bsel];
        const float (*Qc)[128] = Qsm[bsel];
        const float* Vc = Vsm[bsel];
        const float* Gc = Gsm[bsel];

        // load pairs 0 and 1 (tokens 0,1 and 2,3)
        lds_load_kqv8(Kc[0], Qc[0], Vc + 0,  kh16, vloc, sw, k0A, q0A, v0A);
        lds_load_kqv8(Kc[1], Qc[1], Vc + 4,  kh16, vloc, sw, k1A, q1A, v1A);
        gA = *reinterpret_cast<const float4*>(Gc + 0);
        lds_load_kqv8(Kc[2], Qc[2], Vc + 8,  kh16, vloc, sw, k0B, q0B, v0B);
        lds_load_kqv8(Kc[3], Qc[3], Vc + 12, kh16, vloc, sw, k1B, q1B, v1B);
        gB4 = *reinterpret_cast<const float4*>(Gc + 4);

#pragma unroll
        for (int pp = 0; pp < CH_ / 2; pp += 2) {      // pairs pp (A), pp+1 (B)
            step_pair(S, k0A, q0A, v0A, k1A, q1A, v1A, gA, kh16,
                      obase + (size_t)(t0 + 2 * pp)     * (HV_ * DK_),
                      obase + (size_t)(t0 + 2 * pp + 1) * (HV_ * DK_));
            if (pp + 2 < CH_ / 2) {                    // refill A with pair pp+2
                const int ta = 2 * (pp + 2);
                lds_load_kqv8(Kc[ta],     Qc[ta],     Vc + ta * 4,
                              kh16, vloc, sw, k0A, q0A, v0A);
                lds_load_kqv8(Kc[ta + 1], Qc[ta + 1], Vc + (ta + 1) * 4,
                              kh16, vloc, sw, k1A, q1A, v1A);
                gA = *reinterpret_cast<const float4*>(Gc + 2 * ta);
            }
            __builtin_amdgcn_sched_barrier(0);   // pin refill-A ahead of step-B
            step_pair(S, k0B, q0B, v0B, k1B, q1B, v1B, gB4, kh16,
                      obase + (size_t)(t0 + 2 * pp + 2) * (HV_ * DK_),
                      obase + (size_t)(t0 + 2 * pp + 3) * (HV_ * DK_));
            if (pp + 3 < CH_ / 2) {                    // refill B with pair pp+3
                const int tb = 2 * (pp + 3);
                lds_load_kqv8(Kc[tb],     Qc[tb],     Vc + tb * 4,
                              kh16, vloc, sw, k0B, q0B, v0B);
                lds_load_kqv8(Kc[tb + 1], Qc[tb + 1], Vc + (tb + 1) * 4,
                              kh16, vloc, sw, k1B, q1B, v1B);
                gB4 = *reinterpret_cast<const float4*>(Gc + 2 * tb);
            }
        }

        // prefetch chunk c+2 into the buffer we just finished reading
        const int tn = (c + 2 < NCH_) ? (c + 2) * CH_ : (NCH_ - 1) * CH_;
        issue_chunk(tn, bsel);
        // keep the newest 18 vmem ops (10 DMA + 8 o-stores) in flight; all
        // older ops -- incl. chunk c+1's DMA -- are retired in order.
        asm volatile("s_waitcnt vmcnt(18)" ::: "memory");
    }
}

// ---------------------------------------------------------------------------
// Fallback (round-2 monolithic kernel) if workspace is too small.
// ---------------------------------------------------------------------------
__global__ __launch_bounds__(128)
void gdn_prefill_fallback(const float* __restrict__ xqkv, const float* __restrict__ bin,
                          const float* __restrict__ ain, const float* __restrict__ wconv,
                          const float* __restrict__ dtb, const float* __restrict__ alg,
                          float* __restrict__ out)
{
    const int h = blockIdx.x, b = blockIdx.y;
    const int hk = h >> 1;
    const int tid = threadIdx.x, lane = tid & 63, wid = tid >> 6;
    __shared__ __align__(16) float ks[DK_];
    __shared__ __align__(16) float qs[DK_];
    __shared__ float redq[2], redk[2];
    const int qc = hk * DK_ + tid, kc = HK_ * DK_ + hk * DK_ + tid,
              vc = 2 * HK_ * DK_ + h * DK_ + tid;
    float wq[4], wk[4], wv[4];
#pragma unroll
    for (int j = 0; j < 4; ++j) {
        wq[j] = wconv[qc*4+j]; wk[j] = wconv[kc*4+j]; wv[j] = wconv[vc*4+j];
    }
    const float nea = -expf(alg[h]), dbi = dtb[h];
    float hq0=0,hq1=0,hq2=0,hk0=0,hk1=0,hk2=0,hv0=0,hv1=0,hv2=0;
    float Sr[DK_];
#pragma unroll
    for (int k = 0; k < DK_; ++k) Sr[k] = 0.f;
    const size_t row0 = (size_t)b * S_;
    for (int t = 0; t < S_; ++t) {
        const size_t row = row0 + t, xb = row * QKV_;
        const float xq = xqkv[xb+qc], xk = xqkv[xb+kc], xv = xqkv[xb+vc];
        float yq = hq0*wq[0]+hq1*wq[1]+hq2*wq[2]+xq*wq[3];
        float yk = hk0*wk[0]+hk1*wk[1]+hk2*wk[2]+xk*wk[3];
        float yv = hv0*wv[0]+hv1*wv[1]+hv2*wv[2]+xv*wv[3];
        hq0=hq1;hq1=hq2;hq2=xq; hk0=hk1;hk1=hk2;hk2=xk; hv0=hv1;hv1=hv2;hv2=xv;
        yq = yq/(1.f+expf(-yq)); yk = yk/(1.f+expf(-yk)); yv = yv/(1.f+expf(-yv));
        float sq = yq*yq, sk = yk*yk;
#pragma unroll
        for (int off = 32; off >= 1; off >>= 1) {
            sq += __shfl_xor(sq, off, 64); sk += __shfl_xor(sk, off, 64);
        }
        if (lane == 0) { redq[wid] = sq; redk[wid] = sk; }
        __syncthreads();
        const float qn = yq * rsqrtf(redq[0]+redq[1]+EPS_) * SCALE_;
        const float kn = yk * rsqrtf(redk[0]+redk[1]+EPS_);
        ks[tid] = kn; qs[tid] = qn;
        const size_t rab = row * HV_ + h;
        const float av = ain[rab] + dbi;
        const float sp = (av > 20.f) ? av : log1pf(expf(av));
        const float eg = expf(nea * sp);
        const float beta = 1.f/(1.f+expf(-bin[rab]));
        __syncthreads();
        float pred = 0.f;
#pragma unroll
        for (int k4 = 0; k4 < DK_/4; ++k4) {
            const float4 kv = *reinterpret_cast<const float4*>(&ks[k4*4]);
            float s;
            s = Sr[4*k4+0]*eg; Sr[4*k4+0]=s; pred += kv.x*s;
            s = Sr[4*k4+1]*eg; Sr[4*k4+1]=s; pred += kv.y*s;
            s = Sr[4*k4+2]*eg; Sr[4*k4+2]=s; pred += kv.z*s;
            s = Sr[4*k4+3]*eg; Sr[4*k4+3]=s; pred += kv.w*s;
        }
        const float delta = beta * (yv - pred);
        float o = 0.f;
#pragma unroll
        for (int k4 = 0; k4 < DK_/4; ++k4) {
            const float4 kv = *reinterpret_cast<const float4*>(&ks[k4*4]);
            const float4 qv = *reinterpret_cast<const float4*>(&qs[k4*4]);
            float s;
            s = Sr[4*k4+0]+kv.x*delta; Sr[4*k4+0]=s; o += qv.x*s;
            s = Sr[4*k4+1]+kv.y*delta; Sr[4*k4+1]=s; o += qv.y*s;
            s = Sr[4*k4+2]+kv.z*delta; Sr[4*k4+2]=s; o += qv.z*s;
            s = Sr[4*k4+3]+kv.w*delta; Sr[4*k4+3]=s; o += qv.w*s;
        }
        out[rab * DK_ + tid] = o;
    }
}

extern "C" void kernel_launch(void* const* d_in, const int* in_sizes, int n_in,
                              void* d_out, int out_size, void* d_ws, size_t ws_size,
                              hipStream_t stream) {
    const float* xqkv  = (const float*)d_in[0];
    const float* bin   = (const float*)d_in[1];
    const float* ain   = (const float*)d_in[2];
    const float* wconv = (const float*)d_in[3];
    const float* dtb   = (const float*)d_in[4];
    const float* alg   = (const float*)d_in[5];
    float* out = (float*)d_out;

    const size_t Y_BYTES = (size_t)B_ * S_ * QKV_ * 4;         // 134 MB
    const size_t G_BYTES = (size_t)B_ * S_ * HV_ * 8;          // 1 MB (float2)
    const size_t NEEDED  = Y_BYTES + G_BYTES;

    if (ws_size >= NEEDED) {
        float*  Y  = (float*)d_ws;
        float2* GB = (float2*)((char*)d_ws + Y_BYTES);

        preproc_kernel<<<dim3(4, B_ * S_ / 4), 256, 0, stream>>>(xqkv, wconv, Y);
        gating_kernel<<<dim3((B_ * S_ * HV_ + 255) / 256), 256, 0, stream>>>(
            bin, ain, dtb, alg, GB);
        recur_kernel<<<dim3(HV_, B_, 32), 64, 0, stream>>>(Y, GB, out);
    } else {
        gdn_prefill_fallback<<<dim3(HV_, B_), 128, 0, stream>>>(
            xqkv, bin, ain, wconv, dtb, alg, out);
    }
}

// Round 6
// 696.111 us; speedup vs baseline: 1.6034x; 1.6034x over previous
//
#include <hip/hip_runtime.h>
#include <hip/hip_bf16.h>

// Qwen3-Next GatedDeltaNet prefill, B=2, S=2048, HK=16, HV=32, DK=DV=128, K=4.
// Round 10: revert to round-8 structure (650us, 0 bank conflicts, 102MB fetch;
// round-9 TLP x2 regressed: +conflicts, +fetch, +net issue) and REMOVE issue:
// the 4 S-independent pair dots (k1k0, q0k0, q1k0, q1k1) are identical across
// the 32 blocks sharing (b,hk) -> precompute once in dot_kernel into CD
// [b][hk][pair][4] (512 KB), DMA'd per-chunk (1 extra gload4). step_pair now
// does 4 online dots + 4 red8 (was 8+8): ~26% less issue on the serial path.
// LDS ring / vmcnt bookkeeping: 20 loads + 16 stores/chunk -> vmcnt(36).

#define B_    2
#define S_    2048
#define HK_   16
#define HV_   32
#define DK_   128
#define QKV_  8192
#define EPS_  1e-6f
#define SCALE_ 0.08838834764831845f   // 128^-0.5
#define CH_   16
#define NCH_  (S_ / CH_)

#define AS_GLOBAL __attribute__((address_space(1)))
#define AS_LDS    __attribute__((address_space(3)))

__device__ __forceinline__ void gload16(const float* src, float* dst) {
    __builtin_amdgcn_global_load_lds((const AS_GLOBAL void*)src,
                                     (AS_LDS void*)dst, 16, 0, 0);
}
__device__ __forceinline__ void gload4(const float* src, float* dst) {
    __builtin_amdgcn_global_load_lds((const AS_GLOBAL void*)src,
                                     (AS_LDS void*)dst, 4, 0, 0);
}

// 8-lane sum over lanes sharing (lane>>3): all stages VALU-latency DPP.
__device__ __forceinline__ float red8(float x) {
    int t;
    t = __builtin_amdgcn_update_dpp(0, __float_as_int(x), 0xB1, 0xF, 0xF, true);
    x += __int_as_float(t);                               // + lane^1
    t = __builtin_amdgcn_update_dpp(0, __float_as_int(x), 0x4E, 0xF, 0xF, true);
    x += __int_as_float(t);                               // + lane^2
    t = __builtin_amdgcn_update_dpp(0, __float_as_int(x), 0x141, 0xF, 0xF, true);
    x += __int_as_float(t);                               // + lane^4 (via ^7)
    return x;
}

// ---------------------------------------------------------------------------
// Preprocess: y = silu(causal_conv(x)); q/k l2-normalized per 128-ch head,
// q pre-scaled by DK^-0.5. Y layout = x layout: [B*S, 8192].
// grid (4 segs, B*S/4), block 256, 8 ch/thread, 4 tokens/block (rolling hist).
// ---------------------------------------------------------------------------
__global__ __launch_bounds__(256)
void preproc_kernel(const float* __restrict__ x, const float* __restrict__ w,
                    float* __restrict__ Y)
{
    const int seg = blockIdx.x;            // 0:q 1:k 2,3:v
    const int bt0 = blockIdx.y * 4;        // first global row of this block
    const int t0  = bt0 & (S_ - 1);        // token within sequence
    const int tid = threadIdx.x;
    const int c0  = seg * 2048 + tid * 8;

    float4 w4[8];
#pragma unroll
    for (int i = 0; i < 8; ++i)
        w4[i] = *reinterpret_cast<const float4*>(&w[(c0 + i) * 4]);

    float h0[8], h1[8], h2[8], cur[8], y[8];

#pragma unroll
    for (int i = 0; i < 8; ++i) { h0[i] = 0.f; h1[i] = 0.f; h2[i] = 0.f; }
    if (t0 >= 3) {   // t0 is a multiple of 4, so either 0 (all zero) or >=4
        const float* r0 = &x[(size_t)(bt0 - 3) * QKV_ + c0];
        const float* r1 = &x[(size_t)(bt0 - 2) * QKV_ + c0];
        const float* r2 = &x[(size_t)(bt0 - 1) * QKV_ + c0];
#pragma unroll
        for (int i4 = 0; i4 < 2; ++i4) {
            const float4 a = *reinterpret_cast<const float4*>(r0 + i4 * 4);
            const float4 b = *reinterpret_cast<const float4*>(r1 + i4 * 4);
            const float4 c = *reinterpret_cast<const float4*>(r2 + i4 * 4);
            h0[4*i4+0]=a.x; h0[4*i4+1]=a.y; h0[4*i4+2]=a.z; h0[4*i4+3]=a.w;
            h1[4*i4+0]=b.x; h1[4*i4+1]=b.y; h1[4*i4+2]=b.z; h1[4*i4+3]=b.w;
            h2[4*i4+0]=c.x; h2[4*i4+1]=c.y; h2[4*i4+2]=c.z; h2[4*i4+3]=c.w;
        }
    }

#pragma unroll
    for (int tt = 0; tt < 4; ++tt) {
        const float* rc = &x[(size_t)(bt0 + tt) * QKV_ + c0];
#pragma unroll
        for (int i4 = 0; i4 < 2; ++i4) {
            const float4 a = *reinterpret_cast<const float4*>(rc + i4 * 4);
            cur[4*i4+0]=a.x; cur[4*i4+1]=a.y; cur[4*i4+2]=a.z; cur[4*i4+3]=a.w;
        }
#pragma unroll
        for (int i = 0; i < 8; ++i) {
            float v = h0[i]*w4[i].x + h1[i]*w4[i].y + h2[i]*w4[i].z + cur[i]*w4[i].w;
            y[i] = v / (1.f + expf(-v));                 // silu
        }
        if (seg < 2) {                                    // l2norm over 128 ch = 16 lanes
            float s = 0.f;
#pragma unroll
            for (int i = 0; i < 8; ++i) s += y[i] * y[i];
#pragma unroll
            for (int off = 8; off >= 1; off >>= 1)
                s += __shfl_xor(s, off, 64);
            float rn = rsqrtf(s + EPS_);
            if (seg == 0) rn *= SCALE_;
#pragma unroll
            for (int i = 0; i < 8; ++i) y[i] *= rn;
        }
        float4* dst = reinterpret_cast<float4*>(&Y[(size_t)(bt0 + tt) * QKV_ + c0]);
        dst[0] = make_float4(y[0], y[1], y[2], y[3]);
        dst[1] = make_float4(y[4], y[5], y[6], y[7]);
#pragma unroll
        for (int i = 0; i < 8; ++i) { h0[i] = h1[i]; h1[i] = h2[i]; h2[i] = cur[i]; }
    }
}

// ---------------------------------------------------------------------------
// Gating: GB[i] = (exp(-exp(alog)*softplus(a+dt_bias)), sigmoid(b)). [B*S,HV]
// ---------------------------------------------------------------------------
__global__ __launch_bounds__(256)
void gating_kernel(const float* __restrict__ bin, const float* __restrict__ ain,
                   const float* __restrict__ dtb, const float* __restrict__ alg,
                   float2* __restrict__ GB)
{
    const int i = blockIdx.x * 256 + threadIdx.x;
    if (i >= B_ * S_ * HV_) return;
    const int h = i & (HV_ - 1);
    const float av = ain[i] + dtb[h];
    const float sp = (av > 20.f) ? av : log1pf(expf(av));
    GB[i] = make_float2(expf(-expf(alg[h]) * sp), 1.f / (1.f + expf(-bin[i])));
}

// ---------------------------------------------------------------------------
// Pair cross-dots: CD[(b*HK+hk)*S/2 + p] = (k1.k0, q0.k0, q1.k0, q1.k1)
// for tokens (2p, 2p+1). One wave per pair, 2 ch/lane, 6-stage shfl reduce.
// S-independent -> fully parallel; shared by 32 recurrence blocks per (b,hk).
// ---------------------------------------------------------------------------
__global__ __launch_bounds__(256)
void dot_kernel(const float* __restrict__ Y, float4* __restrict__ CD)
{
    const int lane = threadIdx.x & 63;
    const int i    = blockIdx.x * 4 + (threadIdx.x >> 6);   // global pair slot
    const int p    = i & (S_ / 2 - 1);
    const int bh   = i >> 10;                 // S_/2 = 1024 pairs per (b,hk)
    const int hk   = bh & (HK_ - 1);
    const int b    = bh >> 4;
    const int ch   = lane * 2;
    const size_t r0 = (size_t)(b * S_ + 2 * p) * QKV_;
    const int koff = 2048 + hk * DK_ + ch;
    const int qoff = hk * DK_ + ch;

    const float2 k0 = *reinterpret_cast<const float2*>(&Y[r0 + koff]);
    const float2 q0 = *reinterpret_cast<const float2*>(&Y[r0 + qoff]);
    const float2 k1 = *reinterpret_cast<const float2*>(&Y[r0 + QKV_ + koff]);
    const float2 q1 = *reinterpret_cast<const float2*>(&Y[r0 + QKV_ + qoff]);

    float cc  = k1.x * k0.x + k1.y * k0.y;
    float w00 = q0.x * k0.x + q0.y * k0.y;
    float w10 = q1.x * k0.x + q1.y * k0.y;
    float w11 = q1.x * k1.x + q1.y * k1.y;
#pragma unroll
    for (int off = 32; off >= 1; off >>= 1) {
        cc  += __shfl_xor(cc,  off, 64);
        w00 += __shfl_xor(w00, off, 64);
        w10 += __shfl_xor(w10, off, 64);
        w11 += __shfl_xor(w11, off, 64);
    }
    if (lane == 0) CD[i] = make_float4(cc, w00, w10, w11);
}

// ---------------------------------------------------------------------------
// Recurrence helpers
// ---------------------------------------------------------------------------
__device__ __forceinline__ void lds_load_kqv(const float* __restrict__ Kt,
                                             const float* __restrict__ Qt,
                                             const float* __restrict__ Vt,
                                             int kh, int vloc, int sw,
                                             float (&kf)[16], float (&qf)[16],
                                             float& vv)
{
    // read granules in order (r ^ sw): per-instruction lane granules are
    // distinct mod 8 -> conflict-free ds_read_b128 (verified: 0 conflicts).
#pragma unroll
    for (int r = 0; r < 4; ++r) {
        const int idx = r ^ sw;                           // LDS address only
        const float4 kq = *reinterpret_cast<const float4*>(Kt + kh * 16 + idx * 4);
        const float4 qq = *reinterpret_cast<const float4*>(Qt + kh * 16 + idx * 4);
        kf[4*r+0]=kq.x; kf[4*r+1]=kq.y; kf[4*r+2]=kq.z; kf[4*r+3]=kq.w;
        qf[4*r+0]=qq.x; qf[4*r+1]=qq.y; qf[4*r+2]=qq.z; qf[4*r+3]=qq.w;
    }
    vv = Vt[vloc];
}

// One 2-token step (mini-WY). Only the 4 S-dependent dots remain online;
// cross-dots come in via cd = (cc, w00, w10, w11) precomputed by dot_kernel.
__device__ __forceinline__ void step_pair(float (&S)[16],
    const float (&k0)[16], const float (&q0)[16], float v0,
    const float (&k1)[16], const float (&q1)[16], float v1,
    float4 g,                       // (eg0, b0, eg1, b1)
    float4 cd,                      // (k1k0, q0k0, q1k0, q1k1)
    int kh, float* __restrict__ o0p, float* __restrict__ o1p)
{
    float a0 = 0.f, a1 = 0.f, u0 = 0.f, u1 = 0.f;
#pragma unroll
    for (int j = 0; j < 16; ++j) {
        a0 += k0[j] * S[j];
        a1 += k1[j] * S[j];
        u0 += q0[j] * S[j];
        u1 += q1[j] * S[j];
    }
    a0 = red8(a0);  a1 = red8(a1);  u0 = red8(u0);  u1 = red8(u1);

    const float eg0 = g.x, b0 = g.y, eg1 = g.z, b1 = g.w;
    const float cc = cd.x, w00 = cd.y, w10 = cd.z, w11 = cd.w;
    const float d0   = b0 * (v0 - eg0 * a0);
    const float eg01 = eg0 * eg1;
    const float p1   = fmaf(eg1 * cc, d0, eg01 * a1);
    const float d1   = b1 * (v1 - p1);
    const float o0   = fmaf(w00, d0, eg0 * u0);
    const float o1   = fmaf(w11, d1, fmaf(eg1 * w10, d0, eg01 * u1));
    const float bb   = eg1 * d0;
#pragma unroll
    for (int j = 0; j < 16; ++j)
        S[j] = fmaf(eg01, S[j], fmaf(bb, k0[j], d1 * k1[j]));

    if (kh == 0) { *o0p = o0; *o1p = o1; }
}

// ---------------------------------------------------------------------------
// Recurrence: grid (HV, B, 16 v-slices) = 1024 single-wave blocks, 64 threads.
// thread = (vcol = vs*8 + lane>>3, kh = lane&7); owns S[kh*16 .. +15][vcol].
// 16-token chunks staged to LDS (double-buffered) via global_load_lds; the
// chunk c+2 DMA is issued after computing chunk c and kept in flight with
// s_waitcnt vmcnt(36) = 20 loads + 16 o-stores (in-order vmcnt retirement
// guarantees chunk c+1's older loads have landed). Compute runs on PAIRS
// (8 per chunk) with a pair-level A/B register double buffer.
// ---------------------------------------------------------------------------
__global__ __launch_bounds__(64, 1)
void recur_kernel(const float* __restrict__ Y, const float2* __restrict__ GB,
                  const float* __restrict__ CDg, float* __restrict__ out)
{
    const int h    = blockIdx.x;
    const int b    = blockIdx.y;
    const int vs   = blockIdx.z;
    const int hk   = h >> 1;
    const int lane = threadIdx.x;
    const int kh   = lane & 7;
    const int vloc = lane >> 3;
    const int sw   = kh >> 1;

    const int qoff0 = hk * DK_;
    const int koff0 = 2048 + hk * DK_;
    const int voff0 = 4096 + h * DK_ + vs * 8;

    // 34816 B static LDS -> 4 blocks/CU co-resident (4*34816 <= 160 KiB)
    __shared__ __align__(16) float Ksm[2][CH_][128];
    __shared__ __align__(16) float Qsm[2][CH_][128];
    __shared__ __align__(16) float Vsm[2][CH_ * 8];
    __shared__ __align__(16) float Gsm[2][64];
    __shared__ __align__(16) float CDsm[2][64];   // 8 pairs x 4 + dup pad

    const float* rowBase = Y + (size_t)(b * S_) * QKV_;
    const float* gflat   = (const float*)(GB + (size_t)(b * S_) * HV_ + h);
    const float* cdflat  = CDg + (size_t)(b * HK_ + hk) * (S_ / 2) * 4;
    float* obase = out + ((size_t)(b * S_) * HV_ + h) * (size_t)DK_ + vs * 8 + vloc;

    // DMA lane roles
    const int tk = lane >> 5;      // K/Q: which of 2 tokens per 1 KiB instr
    const int gr = lane & 31;      // 16-B granule within a 512-B row

    auto issue_chunk = [&](int t0, int bsel) {
#pragma unroll
        for (int i = 0; i < 8; ++i)     // K: 8 x 16B, 2 tokens each
            gload16(rowBase + (size_t)(t0 + 2 * i + tk) * QKV_ + koff0 + gr * 4,
                    &Ksm[bsel][2 * i][0]);
#pragma unroll
        for (int i = 0; i < 8; ++i)     // Q: 8 x 16B
            gload16(rowBase + (size_t)(t0 + 2 * i + tk) * QKV_ + qoff0 + gr * 4,
                    &Qsm[bsel][2 * i][0]);
#pragma unroll
        for (int i = 0; i < 2; ++i)     // V: 2 x 4B, 8 tokens each
            gload4(rowBase + (size_t)(t0 + i * 8 + (lane >> 3)) * QKV_
                           + voff0 + (lane & 7),
                   &Vsm[bsel][i * 64]);
        // G: 1 x 4B; lanes >=32 duplicate into padding
        gload4(gflat + (size_t)(t0 + ((lane >> 1) & 15)) * (HV_ * 2) + (lane & 1),
               &Gsm[bsel][0]);
        // CD: 1 x 4B; 8 pairs x 4 floats; lanes >=32 duplicate into padding
        gload4(cdflat + (size_t)(t0 / 2) * 4 + (lane & 31),
               &CDsm[bsel][0]);
    };

    float S[16];
#pragma unroll
    for (int j = 0; j < 16; ++j) S[j] = 0.f;

    issue_chunk(0, 0);
    issue_chunk(CH_, 1);
    asm volatile("s_waitcnt vmcnt(20)" ::: "memory");   // chunk 0 landed

    // pair-level A/B register double buffer
    float k0A[16], q0A[16], k1A[16], q1A[16], v0A, v1A;
    float k0B[16], q0B[16], k1B[16], q1B[16], v0B, v1B;
    float4 gA, gB4, cdA, cdB;

    for (int c = 0; c < NCH_; ++c) {
        const int bsel = c & 1;
        const int t0   = c * CH_;
        const float (*Kc)[128] = Ksm[bsel];
        const float (*Qc)[128] = Qsm[bsel];
        const float* Vc  = Vsm[bsel];
        const float* Gc  = Gsm[bsel];
        const float* CDc = CDsm[bsel];

        // load pairs 0 and 1 (tokens 0,1 and 2,3)
        lds_load_kqv(Kc[0], Qc[0], Vc + 0,  kh, vloc, sw, k0A, q0A, v0A);
        lds_load_kqv(Kc[1], Qc[1], Vc + 8,  kh, vloc, sw, k1A, q1A, v1A);
        gA  = *reinterpret_cast<const float4*>(Gc + 0);
        cdA = *reinterpret_cast<const float4*>(CDc + 0);
        lds_load_kqv(Kc[2], Qc[2], Vc + 16, kh, vloc, sw, k0B, q0B, v0B);
        lds_load_kqv(Kc[3], Qc[3], Vc + 24, kh, vloc, sw, k1B, q1B, v1B);
        gB4 = *reinterpret_cast<const float4*>(Gc + 4);
        cdB = *reinterpret_cast<const float4*>(CDc + 4);

#pragma unroll
        for (int pp = 0; pp < CH_ / 2; pp += 2) {      // pairs pp (A), pp+1 (B)
            step_pair(S, k0A, q0A, v0A, k1A, q1A, v1A, gA, cdA, kh,
                      obase + (size_t)(t0 + 2 * pp)     * (HV_ * DK_),
                      obase + (size_t)(t0 + 2 * pp + 1) * (HV_ * DK_));
            if (pp + 2 < CH_ / 2) {                    // refill A with pair pp+2
                const int ta = 2 * (pp + 2);
                lds_load_kqv(Kc[ta],     Qc[ta],     Vc + ta * 8,
                             kh, vloc, sw, k0A, q0A, v0A);
                lds_load_kqv(Kc[ta + 1], Qc[ta + 1], Vc + (ta + 1) * 8,
                             kh, vloc, sw, k1A, q1A, v1A);
                gA  = *reinterpret_cast<const float4*>(Gc + 2 * ta);
                cdA = *reinterpret_cast<const float4*>(CDc + 4 * (pp + 2));
            }
            __builtin_amdgcn_sched_barrier(0);   // pin refill-A ahead of step-B
            step_pair(S, k0B, q0B, v0B, k1B, q1B, v1B, gB4, cdB, kh,
                      obase + (size_t)(t0 + 2 * pp + 2) * (HV_ * DK_),
                      obase + (size_t)(t0 + 2 * pp + 3) * (HV_ * DK_));
            if (pp + 3 < CH_ / 2) {                    // refill B with pair pp+3
                const int tb = 2 * (pp + 3);
                lds_load_kqv(Kc[tb],     Qc[tb],     Vc + tb * 8,
                             kh, vloc, sw, k0B, q0B, v0B);
                lds_load_kqv(Kc[tb + 1], Qc[tb + 1], Vc + (tb + 1) * 8,
                             kh, vloc, sw, k1B, q1B, v1B);
                gB4 = *reinterpret_cast<const float4*>(Gc + 2 * tb);
                cdB = *reinterpret_cast<const float4*>(CDc + 4 * (pp + 3));
            }
        }

        // prefetch chunk c+2 into the buffer we just finished reading
        const int tn = (c + 2 < NCH_) ? (c + 2) * CH_ : (NCH_ - 1) * CH_;
        issue_chunk(tn, bsel);
        // keep the newest 36 vmem ops (20 DMA + 16 o-stores) in flight; all
        // older ops -- incl. chunk c+1's DMA -- are retired in order.
        asm volatile("s_waitcnt vmcnt(36)" ::: "memory");
    }
}

// ---------------------------------------------------------------------------
// Fallback (round-2 monolithic kernel) if workspace is too small.
// ---------------------------------------------------------------------------
__global__ __launch_bounds__(128)
void gdn_prefill_fallback(const float* __restrict__ xqkv, const float* __restrict__ bin,
                          const float* __restrict__ ain, const float* __restrict__ wconv,
                          const float* __restrict__ dtb, const float* __restrict__ alg,
                          float* __restrict__ out)
{
    const int h = blockIdx.x, b = blockIdx.y;
    const int hk = h >> 1;
    const int tid = threadIdx.x, lane = tid & 63, wid = tid >> 6;
    __shared__ __align__(16) float ks[DK_];
    __shared__ __align__(16) float qs[DK_];
    __shared__ float redq[2], redk[2];
    const int qc = hk * DK_ + tid, kc = HK_ * DK_ + hk * DK_ + tid,
              vc = 2 * HK_ * DK_ + h * DK_ + tid;
    float wq[4], wk[4], wv[4];
#pragma unroll
    for (int j = 0; j < 4; ++j) {
        wq[j] = wconv[qc*4+j]; wk[j] = wconv[kc*4+j]; wv[j] = wconv[vc*4+j];
    }
    const float nea = -expf(alg[h]), dbi = dtb[h];
    float hq0=0,hq1=0,hq2=0,hk0=0,hk1=0,hk2=0,hv0=0,hv1=0,hv2=0;
    float Sr[DK_];
#pragma unroll
    for (int k = 0; k < DK_; ++k) Sr[k] = 0.f;
    const size_t row0 = (size_t)b * S_;
    for (int t = 0; t < S_; ++t) {
        const size_t row = row0 + t, xb = row * QKV_;
        const float xq = xqkv[xb+qc], xk = xqkv[xb+kc], xv = xqkv[xb+vc];
        float yq = hq0*wq[0]+hq1*wq[1]+hq2*wq[2]+xq*wq[3];
        float yk = hk0*wk[0]+hk1*wk[1]+hk2*wk[2]+xk*wk[3];
        float yv = hv0*wv[0]+hv1*wv[1]+hv2*wv[2]+xv*wv[3];
        hq0=hq1;hq1=hq2;hq2=xq; hk0=hk1;hk1=hk2;hk2=xk; hv0=hv1;hv1=hv2;hv2=xv;
        yq = yq/(1.f+expf(-yq)); yk = yk/(1.f+expf(-yk)); yv = yv/(1.f+expf(-yv));
        float sq = yq*yq, sk = yk*yk;
#pragma unroll
        for (int off = 32; off >= 1; off >>= 1) {
            sq += __shfl_xor(sq, off, 64); sk += __shfl_xor(sk, off, 64);
        }
        if (lane == 0) { redq[wid] = sq; redk[wid] = sk; }
        __syncthreads();
        const float qn = yq * rsqrtf(redq[0]+redq[1]+EPS_) * SCALE_;
        const float kn = yk * rsqrtf(redk[0]+redk[1]+EPS_);
        ks[tid] = kn; qs[tid] = qn;
        const size_t rab = row * HV_ + h;
        const float av = ain[rab] + dbi;
        const float sp = (av > 20.f) ? av : log1pf(expf(av));
        const float eg = expf(nea * sp);
        const float beta = 1.f/(1.f+expf(-bin[rab]));
        __syncthreads();
        float pred = 0.f;
#pragma unroll
        for (int k4 = 0; k4 < DK_/4; ++k4) {
            const float4 kv = *reinterpret_cast<const float4*>(&ks[k4*4]);
            float s;
            s = Sr[4*k4+0]*eg; Sr[4*k4+0]=s; pred += kv.x*s;
            s = Sr[4*k4+1]*eg; Sr[4*k4+1]=s; pred += kv.y*s;
            s = Sr[4*k4+2]*eg; Sr[4*k4+2]=s; pred += kv.z*s;
            s = Sr[4*k4+3]*eg; Sr[4*k4+3]=s; pred += kv.w*s;
        }
        const float delta = beta * (yv - pred);
        float o = 0.f;
#pragma unroll
        for (int k4 = 0; k4 < DK_/4; ++k4) {
            const float4 kv = *reinterpret_cast<const float4*>(&ks[k4*4]);
            const float4 qv = *reinterpret_cast<const float4*>(&qs[k4*4]);
            float s;
            s = Sr[4*k4+0]+kv.x*delta; Sr[4*k4+0]=s; o += qv.x*s;
            s = Sr[4*k4+1]+kv.y*delta; Sr[4*k4+1]=s; o += qv.y*s;
            s = Sr[4*k4+2]+kv.z*delta; Sr[4*k4+2]=s; o += qv.z*s;
            s = Sr[4*k4+3]+kv.w*delta; Sr[4*k4+3]=s; o += qv.w*s;
        }
        out[rab * DK_ + tid] = o;
    }
}

extern "C" void kernel_launch(void* const* d_in, const int* in_sizes, int n_in,
                              void* d_out, int out_size, void* d_ws, size_t ws_size,
                              hipStream_t stream) {
    const float* xqkv  = (const float*)d_in[0];
    const float* bin   = (const float*)d_in[1];
    const float* ain   = (const float*)d_in[2];
    const float* wconv = (const float*)d_in[3];
    const float* dtb   = (const float*)d_in[4];
    const float* alg   = (const float*)d_in[5];
    float* out = (float*)d_out;

    const size_t Y_BYTES  = (size_t)B_ * S_ * QKV_ * 4;        // 134 MB
    const size_t G_BYTES  = (size_t)B_ * S_ * HV_ * 8;         // 1 MB (float2)
    const size_t CD_BYTES = (size_t)B_ * HK_ * (S_ / 2) * 16;  // 512 KB (float4)
    const size_t NEEDED   = Y_BYTES + G_BYTES + CD_BYTES;

    if (ws_size >= NEEDED) {
        float*  Y  = (float*)d_ws;
        float2* GB = (float2*)((char*)d_ws + Y_BYTES);
        float*  CD = (float*)((char*)d_ws + Y_BYTES + G_BYTES);

        preproc_kernel<<<dim3(4, B_ * S_ / 4), 256, 0, stream>>>(xqkv, wconv, Y);
        gating_kernel<<<dim3((B_ * S_ * HV_ + 255) / 256), 256, 0, stream>>>(
            bin, ain, dtb, alg, GB);
        dot_kernel<<<dim3(B_ * HK_ * (S_ / 2) / 4), 256, 0, stream>>>(
            Y, (float4*)CD);
        recur_kernel<<<dim3(HV_, B_, 16), 64, 0, stream>>>(Y, GB, CD, out);
    } else {
        gdn_prefill_fallback<<<dim3(HV_, B_), 128, 0, stream>>>(
            xqkv, bin, ain, wconv, dtb, alg, out);
    }
}

// Round 8
// 690.566 us; speedup vs baseline: 1.6163x; 1.0080x over previous
//
#include <hip/hip_runtime.h>
#include <hip/hip_bf16.h>

// Qwen3-Next GatedDeltaNet prefill, B=2, S=2048, HK=16, HV=32, DK=DV=128, K=4.
// Round 12: fix round-11's LDS overwrite race. The g==3 chunk-prefetch DMA
// targets the SAME buffer the group-3 resolve was still reading (V/G/CD) ->
// intermittent corruption (absmax 5.7e-2). Fix: (1) hoist each group's
// V/G/CD/gating LDS reads to the top of the group body (into registers before
// any DMA can land), (2) s_waitcnt lgkmcnt(0) before issue_chunk at g==3 --
// hard guarantee the ds_reads completed before the first overwriting DMA.
// WY-4 math, q-early/k-late refills, vmcnt(32) ledger unchanged (at the wait:
// newest 32 = 20 prefetch loads + 12 stores of groups 0-2; group-3 stores
// issue after the wait; chunk c+1's loads are older -> retired).

#define B_    2
#define S_    2048
#define HK_   16
#define HV_   32
#define DK_   128
#define QKV_  8192
#define EPS_  1e-6f
#define SCALE_ 0.08838834764831845f   // 128^-0.5
#define CH_   16
#define NCH_  (S_ / CH_)

#define AS_GLOBAL __attribute__((address_space(1)))
#define AS_LDS    __attribute__((address_space(3)))

__device__ __forceinline__ void gload16(const float* src, float* dst) {
    __builtin_amdgcn_global_load_lds((const AS_GLOBAL void*)src,
                                     (AS_LDS void*)dst, 16, 0, 0);
}
__device__ __forceinline__ void gload4(const float* src, float* dst) {
    __builtin_amdgcn_global_load_lds((const AS_GLOBAL void*)src,
                                     (AS_LDS void*)dst, 4, 0, 0);
}

// 8-lane sum over lanes sharing (lane>>3): all stages VALU-latency DPP.
__device__ __forceinline__ float red8(float x) {
    int t;
    t = __builtin_amdgcn_update_dpp(0, __float_as_int(x), 0xB1, 0xF, 0xF, true);
    x += __int_as_float(t);                               // + lane^1
    t = __builtin_amdgcn_update_dpp(0, __float_as_int(x), 0x4E, 0xF, 0xF, true);
    x += __int_as_float(t);                               // + lane^2
    t = __builtin_amdgcn_update_dpp(0, __float_as_int(x), 0x141, 0xF, 0xF, true);
    x += __int_as_float(t);                               // + lane^4 (via ^7)
    return x;
}

// ---------------------------------------------------------------------------
// Preprocess: y = silu(causal_conv(x)); q/k l2-normalized per 128-ch head,
// q pre-scaled by DK^-0.5. Y layout = x layout: [B*S, 8192].
// ---------------------------------------------------------------------------
__global__ __launch_bounds__(256)
void preproc_kernel(const float* __restrict__ x, const float* __restrict__ w,
                    float* __restrict__ Y)
{
    const int seg = blockIdx.x;            // 0:q 1:k 2,3:v
    const int bt0 = blockIdx.y * 4;        // first global row of this block
    const int t0  = bt0 & (S_ - 1);        // token within sequence
    const int tid = threadIdx.x;
    const int c0  = seg * 2048 + tid * 8;

    float4 w4[8];
#pragma unroll
    for (int i = 0; i < 8; ++i)
        w4[i] = *reinterpret_cast<const float4*>(&w[(c0 + i) * 4]);

    float h0[8], h1[8], h2[8], cur[8], y[8];

#pragma unroll
    for (int i = 0; i < 8; ++i) { h0[i] = 0.f; h1[i] = 0.f; h2[i] = 0.f; }
    if (t0 >= 3) {   // t0 is a multiple of 4, so either 0 (all zero) or >=4
        const float* r0 = &x[(size_t)(bt0 - 3) * QKV_ + c0];
        const float* r1 = &x[(size_t)(bt0 - 2) * QKV_ + c0];
        const float* r2 = &x[(size_t)(bt0 - 1) * QKV_ + c0];
#pragma unroll
        for (int i4 = 0; i4 < 2; ++i4) {
            const float4 a = *reinterpret_cast<const float4*>(r0 + i4 * 4);
            const float4 b = *reinterpret_cast<const float4*>(r1 + i4 * 4);
            const float4 c = *reinterpret_cast<const float4*>(r2 + i4 * 4);
            h0[4*i4+0]=a.x; h0[4*i4+1]=a.y; h0[4*i4+2]=a.z; h0[4*i4+3]=a.w;
            h1[4*i4+0]=b.x; h1[4*i4+1]=b.y; h1[4*i4+2]=b.z; h1[4*i4+3]=b.w;
            h2[4*i4+0]=c.x; h2[4*i4+1]=c.y; h2[4*i4+2]=c.z; h2[4*i4+3]=c.w;
        }
    }

#pragma unroll
    for (int tt = 0; tt < 4; ++tt) {
        const float* rc = &x[(size_t)(bt0 + tt) * QKV_ + c0];
#pragma unroll
        for (int i4 = 0; i4 < 2; ++i4) {
            const float4 a = *reinterpret_cast<const float4*>(rc + i4 * 4);
            cur[4*i4+0]=a.x; cur[4*i4+1]=a.y; cur[4*i4+2]=a.z; cur[4*i4+3]=a.w;
        }
#pragma unroll
        for (int i = 0; i < 8; ++i) {
            float v = h0[i]*w4[i].x + h1[i]*w4[i].y + h2[i]*w4[i].z + cur[i]*w4[i].w;
            y[i] = v / (1.f + expf(-v));                 // silu
        }
        if (seg < 2) {                                    // l2norm over 128 ch = 16 lanes
            float s = 0.f;
#pragma unroll
            for (int i = 0; i < 8; ++i) s += y[i] * y[i];
#pragma unroll
            for (int off = 8; off >= 1; off >>= 1)
                s += __shfl_xor(s, off, 64);
            float rn = rsqrtf(s + EPS_);
            if (seg == 0) rn *= SCALE_;
#pragma unroll
            for (int i = 0; i < 8; ++i) y[i] *= rn;
        }
        float4* dst = reinterpret_cast<float4*>(&Y[(size_t)(bt0 + tt) * QKV_ + c0]);
        dst[0] = make_float4(y[0], y[1], y[2], y[3]);
        dst[1] = make_float4(y[4], y[5], y[6], y[7]);
#pragma unroll
        for (int i = 0; i < 8; ++i) { h0[i] = h1[i]; h1[i] = h2[i]; h2[i] = cur[i]; }
    }
}

// ---------------------------------------------------------------------------
// Gating: GB[i] = (exp(-exp(alog)*softplus(a+dt_bias)), sigmoid(b)). [B*S,HV]
// ---------------------------------------------------------------------------
__global__ __launch_bounds__(256)
void gating_kernel(const float* __restrict__ bin, const float* __restrict__ ain,
                   const float* __restrict__ dtb, const float* __restrict__ alg,
                   float2* __restrict__ GB)
{
    const int i = blockIdx.x * 256 + threadIdx.x;
    if (i >= B_ * S_ * HV_) return;
    const int h = i & (HV_ - 1);
    const float av = ain[i] + dtb[h];
    const float sp = (av > 20.f) ? av : log1pf(expf(av));
    GB[i] = make_float2(expf(-expf(alg[h]) * sp), 1.f / (1.f + expf(-bin[i])));
}

// ---------------------------------------------------------------------------
// Group cross-dots for 4-token WY: per (b,hk,grp) with tokens 4g..4g+3,
// CD[...16] = [c10,c20,c21,c30,c31,c32, w00,w10,w11,w20,w21,w22,w30..w33]
// where cij = k_i.k_j, wij = q_i.k_j. One wave per group, 2 ch/lane.
// ---------------------------------------------------------------------------
__global__ __launch_bounds__(256)
void dot_kernel(const float* __restrict__ Y, float4* __restrict__ CD4)
{
    const int lane = threadIdx.x & 63;
    const int i    = blockIdx.x * 4 + (threadIdx.x >> 6);   // global group slot
    const int grp  = i & 511;                 // 512 groups per (b,hk)
    const int bh   = i >> 9;
    const int hk   = bh & (HK_ - 1);
    const int b    = bh >> 4;
    const int ch   = lane * 2;
    const size_t r0 = (size_t)(b * S_ + grp * 4) * QKV_;
    const int koff = 2048 + hk * DK_ + ch;
    const int qoff = hk * DK_ + ch;

    float2 k0 = *reinterpret_cast<const float2*>(Y + r0 + 0 * QKV_ + koff);
    float2 k1 = *reinterpret_cast<const float2*>(Y + r0 + 1 * QKV_ + koff);
    float2 k2 = *reinterpret_cast<const float2*>(Y + r0 + 2 * QKV_ + koff);
    float2 k3 = *reinterpret_cast<const float2*>(Y + r0 + 3 * QKV_ + koff);
    float2 q0 = *reinterpret_cast<const float2*>(Y + r0 + 0 * QKV_ + qoff);
    float2 q1 = *reinterpret_cast<const float2*>(Y + r0 + 1 * QKV_ + qoff);
    float2 q2 = *reinterpret_cast<const float2*>(Y + r0 + 2 * QKV_ + qoff);
    float2 q3 = *reinterpret_cast<const float2*>(Y + r0 + 3 * QKV_ + qoff);

    float d[16];
    d[0]  = k1.x*k0.x + k1.y*k0.y;   // c10
    d[1]  = k2.x*k0.x + k2.y*k0.y;   // c20
    d[2]  = k2.x*k1.x + k2.y*k1.y;   // c21
    d[3]  = k3.x*k0.x + k3.y*k0.y;   // c30
    d[4]  = k3.x*k1.x + k3.y*k1.y;   // c31
    d[5]  = k3.x*k2.x + k3.y*k2.y;   // c32
    d[6]  = q0.x*k0.x + q0.y*k0.y;   // w00
    d[7]  = q1.x*k0.x + q1.y*k0.y;   // w10
    d[8]  = q1.x*k1.x + q1.y*k1.y;   // w11
    d[9]  = q2.x*k0.x + q2.y*k0.y;   // w20
    d[10] = q2.x*k1.x + q2.y*k1.y;   // w21
    d[11] = q2.x*k2.x + q2.y*k2.y;   // w22
    d[12] = q3.x*k0.x + q3.y*k0.y;   // w30
    d[13] = q3.x*k1.x + q3.y*k1.y;   // w31
    d[14] = q3.x*k2.x + q3.y*k2.y;   // w32
    d[15] = q3.x*k3.x + q3.y*k3.y;   // w33
#pragma unroll
    for (int t = 0; t < 16; ++t)
#pragma unroll
        for (int off = 32; off >= 1; off >>= 1)
            d[t] += __shfl_xor(d[t], off, 64);

    if (lane == 0) {
        CD4[(size_t)i * 4 + 0] = make_float4(d[0],  d[1],  d[2],  d[3]);
        CD4[(size_t)i * 4 + 1] = make_float4(d[4],  d[5],  d[6],  d[7]);
        CD4[(size_t)i * 4 + 2] = make_float4(d[8],  d[9],  d[10], d[11]);
        CD4[(size_t)i * 4 + 3] = make_float4(d[12], d[13], d[14], d[15]);
    }
}

// ---------------------------------------------------------------------------
// Recurrence: grid (HV, B, 16 v-slices) = 1024 single-wave blocks, 64 threads.
// thread = (vcol = vs*8 + lane>>3, kh = lane&7); owns S[kh*16 .. +15][vcol].
// 16-token chunks staged to LDS (double-buffered, global_load_lds, 20 loads/
// chunk); compute in 4-token WY groups: group scalars (V/G/CD) -> u/a-dots ->
// red8 x8 -> [g==3: lgkmcnt(0); prefetch c+2; vmcnt(32)] -> q-refill ->
// resolve(+4 stores) -> merged S-update -> k-refill.
// ---------------------------------------------------------------------------
__global__ __launch_bounds__(64, 1)
void recur_kernel(const float* __restrict__ Y, const float2* __restrict__ GB,
                  const float* __restrict__ CDg, float* __restrict__ out)
{
    const int h    = blockIdx.x;
    const int b    = blockIdx.y;
    const int vs   = blockIdx.z;
    const int hk   = h >> 1;
    const int lane = threadIdx.x;
    const int kh   = lane & 7;
    const int vloc = lane >> 3;
    const int sw   = kh >> 1;

    const int qoff0 = hk * DK_;
    const int koff0 = 2048 + hk * DK_;
    const int voff0 = 4096 + h * DK_ + vs * 8;

    // 34816 B static LDS -> 4 blocks/CU co-resident
    __shared__ __align__(16) float Ksm[2][CH_][128];
    __shared__ __align__(16) float Qsm[2][CH_][128];
    __shared__ __align__(16) float Vsm[2][CH_ * 8];
    __shared__ __align__(16) float Gsm[2][64];
    __shared__ __align__(16) float CDsm[2][64];   // 4 groups x 16 floats

    const float* rowBase = Y + (size_t)(b * S_) * QKV_;
    const float* gflat   = (const float*)(GB + (size_t)(b * S_) * HV_ + h);
    const float* cdflat  = CDg + (size_t)(b * HK_ + hk) * 512 * 16;
    float* obase = out + ((size_t)(b * S_) * HV_ + h) * (size_t)DK_ + vs * 8 + vloc;

    // DMA lane roles
    const int tk = lane >> 5;      // K/Q: which of 2 tokens per 1 KiB instr
    const int gr = lane & 31;      // 16-B granule within a 512-B row

    auto issue_chunk = [&](int t0, int bsel) {
#pragma unroll
        for (int i = 0; i < 8; ++i)     // K: 8 x 16B, 2 tokens each
            gload16(rowBase + (size_t)(t0 + 2 * i + tk) * QKV_ + koff0 + gr * 4,
                    &Ksm[bsel][2 * i][0]);
#pragma unroll
        for (int i = 0; i < 8; ++i)     // Q: 8 x 16B
            gload16(rowBase + (size_t)(t0 + 2 * i + tk) * QKV_ + qoff0 + gr * 4,
                    &Qsm[bsel][2 * i][0]);
#pragma unroll
        for (int i = 0; i < 2; ++i)     // V: 2 x 4B, 8 tokens each
            gload4(rowBase + (size_t)(t0 + i * 8 + (lane >> 3)) * QKV_
                           + voff0 + (lane & 7),
                   &Vsm[bsel][i * 64]);
        // G: 1 x 4B; lanes >=32 duplicate into padding
        gload4(gflat + (size_t)(t0 + ((lane >> 1) & 15)) * (HV_ * 2) + (lane & 1),
               &Gsm[bsel][0]);
        // CD: 1 x 4B; 4 groups x 16 floats = 64 floats, full lane coverage
        gload4(cdflat + (size_t)(t0 / 4) * 16 + lane, &CDsm[bsel][0]);
    };

    float S[16];
#pragma unroll
    for (int j = 0; j < 16; ++j) S[j] = 0.f;

    issue_chunk(0, 0);
    issue_chunk(CH_, 1);
    asm volatile("s_waitcnt vmcnt(20)" ::: "memory");   // chunk 0 landed

    float kf[4][16], qf[4][16];
    // preload group 0 of chunk 0
#pragma unroll
    for (int i = 0; i < 4; ++i)
#pragma unroll
        for (int r = 0; r < 4; ++r) {
            const int idx = r ^ sw;
            const float4 kq = *reinterpret_cast<const float4*>(&Ksm[0][i][kh*16 + idx*4]);
            const float4 qq = *reinterpret_cast<const float4*>(&Qsm[0][i][kh*16 + idx*4]);
            kf[i][4*r+0]=kq.x; kf[i][4*r+1]=kq.y; kf[i][4*r+2]=kq.z; kf[i][4*r+3]=kq.w;
            qf[i][4*r+0]=qq.x; qf[i][4*r+1]=qq.y; qf[i][4*r+2]=qq.z; qf[i][4*r+3]=qq.w;
        }

    for (int c = 0; c < NCH_; ++c) {
        const int bsel = c & 1;
        const int t0   = c * CH_;
        const float (*Kc)[128] = Ksm[bsel];
        const float (*Qc)[128] = Qsm[bsel];
        const float (*Kn)[128] = Ksm[bsel ^ 1];
        const float (*Qn)[128] = Qsm[bsel ^ 1];
        const float* Vc  = Vsm[bsel];
        const float* Gc  = Gsm[bsel];
        const float* CDc = CDsm[bsel];

#pragma unroll
        for (int g = 0; g < 4; ++g) {
            // ---- group scalars FIRST: this buffer is the g==3 DMA target ----
            const float4 ga  = *reinterpret_cast<const float4*>(Gc + 8*g);      // e0,b0,e1,b1
            const float4 gbv = *reinterpret_cast<const float4*>(Gc + 8*g + 4);  // e2,b2,e3,b3
            const float4 cd0 = *reinterpret_cast<const float4*>(CDc + 16*g);      // c10,c20,c21,c30
            const float4 cd1 = *reinterpret_cast<const float4*>(CDc + 16*g + 4);  // c31,c32,w00,w10
            const float4 cd2 = *reinterpret_cast<const float4*>(CDc + 16*g + 8);  // w11,w20,w21,w22
            const float4 cd3 = *reinterpret_cast<const float4*>(CDc + 16*g + 12); // w30,w31,w32,w33
            const float v0 = Vc[(4*g+0)*8 + vloc], v1 = Vc[(4*g+1)*8 + vloc];
            const float v2 = Vc[(4*g+2)*8 + vloc], v3 = Vc[(4*g+3)*8 + vloc];

            // ---- u-dots (q prefetched long ago), then a-dots ----
            float u0=0.f,u1=0.f,u2=0.f,u3=0.f;
#pragma unroll
            for (int j = 0; j < 16; ++j) {
                u0 += qf[0][j]*S[j]; u1 += qf[1][j]*S[j];
                u2 += qf[2][j]*S[j]; u3 += qf[3][j]*S[j];
            }
            float a0=0.f,a1=0.f,a2=0.f,a3=0.f;
#pragma unroll
            for (int j = 0; j < 16; ++j) {
                a0 += kf[0][j]*S[j]; a1 += kf[1][j]*S[j];
                a2 += kf[2][j]*S[j]; a3 += kf[3][j]*S[j];
            }
            u0=red8(u0); u1=red8(u1); u2=red8(u2); u3=red8(u3);
            a0=red8(a0); a1=red8(a1); a2=red8(a2); a3=red8(a3);

            if (g == 3) {   // chunk-level prefetch + ring wait
                // HARD guarantee: group scalars (V/G/CD ds_reads) are in
                // registers before any DMA targeting this buffer is issued.
                asm volatile("s_waitcnt lgkmcnt(0)" ::: "memory");
                const int tn = (c + 2 < NCH_) ? (c + 2) * CH_ : (NCH_ - 1) * CH_;
                issue_chunk(tn, bsel);
                asm volatile("s_waitcnt vmcnt(32)" ::: "memory");
            }
            // ---- q-refill for next group (qf dead after u-dots) ----
            {
                const float (*Qs)[128] = (g == 3) ? Qn : Qc;
                const int gb = (g == 3) ? 0 : (g + 1) * 4;
#pragma unroll
                for (int i = 0; i < 4; ++i)
#pragma unroll
                    for (int r = 0; r < 4; ++r) {
                        const int idx = r ^ sw;
                        const float4 qq = *reinterpret_cast<const float4*>(
                            &Qs[gb + i][kh*16 + idx*4]);
                        qf[i][4*r+0]=qq.x; qf[i][4*r+1]=qq.y;
                        qf[i][4*r+2]=qq.z; qf[i][4*r+3]=qq.w;
                    }
            }
            __builtin_amdgcn_sched_barrier(0);

            // ---- resolve (scalar, per-lane redundant) + stores ----
            const float e0=ga.x, bb0=ga.y, e1=ga.z, bb1=ga.w;
            const float e2=gbv.x, bb2=gbv.y, e3=gbv.z, bb3=gbv.w;
            const float c10=cd0.x, c20=cd0.y, c21=cd0.z, c30=cd0.w;
            const float c31=cd1.x, c32=cd1.y, w00=cd1.z, w10=cd1.w;
            const float w11=cd2.x, w20=cd2.y, w21=cd2.z, w22=cd2.w;
            const float w30=cd3.x, w31=cd3.y, w32=cd3.z, w33=cd3.w;

            const float e01 = e0*e1, e12 = e1*e2, e23 = e2*e3;
            const float e012 = e01*e2, e123 = e12*e3, e0123 = e012*e3;
            const float d0 = bb0 * (v0 - e0*a0);
            const float d1 = bb1 * (v1 - e01*a1 - e1*c10*d0);
            const float d2 = bb2 * (v2 - e012*a2 - e12*c20*d0 - e2*c21*d1);
            const float d3 = bb3 * (v3 - e0123*a3 - e123*c30*d0 - e23*c31*d1
                                       - e3*c32*d2);
            const float o0 = fmaf(w00, d0, e0*u0);
            const float o1 = fmaf(w11, d1, fmaf(e1*w10, d0, e01*u1));
            const float o2 = fmaf(w22, d2, fmaf(e2*w21, d1,
                              fmaf(e12*w20, d0, e012*u2)));
            const float o3 = fmaf(w33, d3, fmaf(e3*w32, d2,
                              fmaf(e23*w31, d1, fmaf(e123*w30, d0, e0123*u3))));
            if (kh == 0) {
                float* op = obase + (size_t)(t0 + 4*g) * (HV_ * DK_);
                op[0]                 = o0;
                op[1 * HV_ * DK_]     = o1;
                op[2 * HV_ * DK_]     = o2;
                op[3 * HV_ * DK_]     = o3;
            }

            // ---- merged S-update ----
            const float f0 = e123*d0, f1 = e23*d1, f2 = e3*d2;
#pragma unroll
            for (int j = 0; j < 16; ++j)
                S[j] = fmaf(e0123, S[j],
                        fmaf(f0, kf[0][j],
                          fmaf(f1, kf[1][j],
                            fmaf(f2, kf[2][j], d3*kf[3][j]))));

            // ---- k-refill for next group (kf dead after update) ----
            {
                const float (*Ks)[128] = (g == 3) ? Kn : Kc;
                const int gb = (g == 3) ? 0 : (g + 1) * 4;
#pragma unroll
                for (int i = 0; i < 4; ++i)
#pragma unroll
                    for (int r = 0; r < 4; ++r) {
                        const int idx = r ^ sw;
                        const float4 kq = *reinterpret_cast<const float4*>(
                            &Ks[gb + i][kh*16 + idx*4]);
                        kf[i][4*r+0]=kq.x; kf[i][4*r+1]=kq.y;
                        kf[i][4*r+2]=kq.z; kf[i][4*r+3]=kq.w;
                    }
            }
            __builtin_amdgcn_sched_barrier(0);
        }
    }
}

// ---------------------------------------------------------------------------
// Fallback (round-2 monolithic kernel) if workspace is too small.
// ---------------------------------------------------------------------------
__global__ __launch_bounds__(128)
void gdn_prefill_fallback(const float* __restrict__ xqkv, const float* __restrict__ bin,
                          const float* __restrict__ ain, const float* __restrict__ wconv,
                          const float* __restrict__ dtb, const float* __restrict__ alg,
                          float* __restrict__ out)
{
    const int h = blockIdx.x, b = blockIdx.y;
    const int hk = h >> 1;
    const int tid = threadIdx.x, lane = tid & 63, wid = tid >> 6;
    __shared__ __align__(16) float ks[DK_];
    __shared__ __align__(16) float qs[DK_];
    __shared__ float redq[2], redk[2];
    const int qc = hk * DK_ + tid, kc = HK_ * DK_ + hk * DK_ + tid,
              vc = 2 * HK_ * DK_ + h * DK_ + tid;
    float wq[4], wk[4], wv[4];
#pragma unroll
    for (int j = 0; j < 4; ++j) {
        wq[j] = wconv[qc*4+j]; wk[j] = wconv[kc*4+j]; wv[j] = wconv[vc*4+j];
    }
    const float nea = -expf(alg[h]), dbi = dtb[h];
    float hq0=0,hq1=0,hq2=0,hk0=0,hk1=0,hk2=0,hv0=0,hv1=0,hv2=0;
    float Sr[DK_];
#pragma unroll
    for (int k = 0; k < DK_; ++k) Sr[k] = 0.f;
    const size_t row0 = (size_t)b * S_;
    for (int t = 0; t < S_; ++t) {
        const size_t row = row0 + t, xb = row * QKV_;
        const float xq = xqkv[xb+qc], xk = xqkv[xb+kc], xv = xqkv[xb+vc];
        float yq = hq0*wq[0]+hq1*wq[1]+hq2*wq[2]+xq*wq[3];
        float yk = hk0*wk[0]+hk1*wk[1]+hk2*wk[2]+xk*wk[3];
        float yv = hv0*wv[0]+hv1*wv[1]+hv2*wv[2]+xv*wv[3];
        hq0=hq1;hq1=hq2;hq2=xq; hk0=hk1;hk1=hk2;hk2=xk; hv0=hv1;hv1=hv2;hv2=xv;
        yq = yq/(1.f+expf(-yq)); yk = yk/(1.f+expf(-yk)); yv = yv/(1.f+expf(-yv));
        float sq = yq*yq, sk = yk*yk;
#pragma unroll
        for (int off = 32; off >= 1; off >>= 1) {
            sq += __shfl_xor(sq, off, 64); sk += __shfl_xor(sk, off, 64);
        }
        if (lane == 0) { redq[wid] = sq; redk[wid] = sk; }
        __syncthreads();
        const float qn = yq * rsqrtf(redq[0]+redq[1]+EPS_) * SCALE_;
        const float kn = yk * rsqrtf(redk[0]+redk[1]+EPS_);
        ks[tid] = kn; qs[tid] = qn;
        const size_t rab = row * HV_ + h;
        const float av = ain[rab] + dbi;
        const float sp = (av > 20.f) ? av : log1pf(expf(av));
        const float eg = expf(nea * sp);
        const float beta = 1.f/(1.f+expf(-bin[rab]));
        __syncthreads();
        float pred = 0.f;
#pragma unroll
        for (int k4 = 0; k4 < DK_/4; ++k4) {
            const float4 kv = *reinterpret_cast<const float4*>(&ks[k4*4]);
            float s;
            s = Sr[4*k4+0]*eg; Sr[4*k4+0]=s; pred += kv.x*s;
            s = Sr[4*k4+1]*eg; Sr[4*k4+1]=s; pred += kv.y*s;
            s = Sr[4*k4+2]*eg; Sr[4*k4+2]=s; pred += kv.z*s;
            s = Sr[4*k4+3]*eg; Sr[4*k4+3]=s; pred += kv.w*s;
        }
        const float delta = beta * (yv - pred);
        float o = 0.f;
#pragma unroll
        for (int k4 = 0; k4 < DK_/4; ++k4) {
            const float4 kv = *reinterpret_cast<const float4*>(&ks[k4*4]);
            const float4 qv = *reinterpret_cast<const float4*>(&qs[k4*4]);
            float s;
            s = Sr[4*k4+0]+kv.x*delta; Sr[4*k4+0]=s; o += qv.x*s;
            s = Sr[4*k4+1]+kv.y*delta; Sr[4*k4+1]=s; o += qv.y*s;
            s = Sr[4*k4+2]+kv.z*delta; Sr[4*k4+2]=s; o += qv.z*s;
            s = Sr[4*k4+3]+kv.w*delta; Sr[4*k4+3]=s; o += qv.w*s;
        }
        out[rab * DK_ + tid] = o;
    }
}

extern "C" void kernel_launch(void* const* d_in, const int* in_sizes, int n_in,
                              void* d_out, int out_size, void* d_ws, size_t ws_size,
                              hipStream_t stream) {
    const float* xqkv  = (const float*)d_in[0];
    const float* bin   = (const float*)d_in[1];
    const float* ain   = (const float*)d_in[2];
    const float* wconv = (const float*)d_in[3];
    const float* dtb   = (const float*)d_in[4];
    const float* alg   = (const float*)d_in[5];
    float* out = (float*)d_out;

    const size_t Y_BYTES  = (size_t)B_ * S_ * QKV_ * 4;        // 134 MB
    const size_t G_BYTES  = (size_t)B_ * S_ * HV_ * 8;         // 1 MB (float2)
    const size_t CD_BYTES = (size_t)B_ * HK_ * 512 * 16 * 4;   // 1 MB
    const size_t NEEDED   = Y_BYTES + G_BYTES + CD_BYTES;

    if (ws_size >= NEEDED) {
        float*  Y  = (float*)d_ws;
        float2* GB = (float2*)((char*)d_ws + Y_BYTES);
        float*  CD = (float*)((char*)d_ws + Y_BYTES + G_BYTES);

        preproc_kernel<<<dim3(4, B_ * S_ / 4), 256, 0, stream>>>(xqkv, wconv, Y);
        gating_kernel<<<dim3((B_ * S_ * HV_ + 255) / 256), 256, 0, stream>>>(
            bin, ain, dtb, alg, GB);
        dot_kernel<<<dim3(B_ * HK_ * 512 / 4), 256, 0, stream>>>(
            Y, (float4*)CD);
        recur_kernel<<<dim3(HV_, B_, 16), 64, 0, stream>>>(Y, GB, CD, out);
    } else {
        gdn_prefill_fallback<<<dim3(HV_, B_), 128, 0, stream>>>(
            xqkv, bin, ain, wconv, dtb, alg, out);
    }
}